// Round 2
// baseline (1997.128 us; speedup 1.0000x reference)
//
#include <hip/hip_runtime.h>

#define BLOCK 256
#define GG 8            // nodes per block; 100000 % 8 == 0 -> 12500 blocks
#define ROWS 48         // 6 * GG
#define SMEM_FLOATS 6144  // AT half: [128][48] = 6144 floats = 24 KB; A2 [8][260]=2080 aliased

__device__ __forceinline__ float sigm(float x) { return 1.0f / (1.0f + __expf(-x)); }

// W1T[256][256]: k<128 x_self, k>=128 neigh; j<128 sigmoid (Wl1/Wr1), j>=128 spike (Wlt1/Wrt1)
// W2T[256][128]: k<128 h0p,    k>=128 neigh2; j<64 sigmoid (Wl2/Wr2),  j>=64  spike (Wlt2/Wrt2)
__global__ void pack_weights_k(const float* __restrict__ Wl1, const float* __restrict__ Wr1,
                               const float* __restrict__ Wlt1, const float* __restrict__ Wrt1,
                               const float* __restrict__ Wl2, const float* __restrict__ Wr2,
                               const float* __restrict__ Wlt2, const float* __restrict__ Wrt2,
                               float* __restrict__ W1T, float* __restrict__ W2T) {
  int idx = blockIdx.x * BLOCK + threadIdx.x;
  if (idx < 256 * 256) {
    int k = idx >> 8, j = idx & 255;
    int jj = j & 127, kk = k & 127;
    const float* src = (j < 128) ? ((k < 128) ? Wl1 : Wr1)
                                 : ((k < 128) ? Wlt1 : Wrt1);
    W1T[idx] = src[jj * 128 + kk];
  } else {
    int i2 = idx - 256 * 256;
    if (i2 < 256 * 128) {
      int k = i2 >> 7, j = i2 & 127;
      int jj = j & 63, kk = k & 127;
      const float* src = (j < 64) ? ((k < 128) ? Wl2 : Wr2)
                                  : ((k < 128) ? Wlt2 : Wrt2);
      W2T[i2] = src[jj * 128 + kk];
    }
  }
}

__global__ __launch_bounds__(BLOCK, 5)
void signn_fused_k(const float* __restrict__ h0, const float* __restrict__ h1,
                   const float* __restrict__ h2, const float* __restrict__ W1T,
                   const float* __restrict__ W2T, float* __restrict__ out) {
  __shared__ float sm[SMEM_FLOATS];
  float* AT = sm;   // [128][48] K-half staging, k-major
  float* A2 = sm;   // [8][260]  layer-2 A, aliased after layer-1 (barrier-separated)

  const int tid = threadIdx.x;
  const int n0 = blockIdx.x * GG;
  const int tj = tid & 63;   // cols 4*tj..4*tj+3 (0..255)
  const int tm = tid >> 6;   // wave id -> rows 12*tm..12*tm+11
  const int m0 = tm * 12;

  float acc[12][4];
  #pragma unroll
  for (int mm = 0; mm < 12; ++mm) {
    acc[mm][0] = 0.f; acc[mm][1] = 0.f; acc[mm][2] = 0.f; acc[mm][3] = 0.f;
  }

  // ---------------- stage half 0: x_self (k = 0..127) ----------------
  // m-fastest: consecutive lanes -> consecutive m -> conflict-free LDS writes
  for (int it = tid; it < ROWS * 32; it += BLOCK) {
    const unsigned m = (unsigned)it % 48u;
    const unsigned ch = (unsigned)it / 48u;
    const int g = (int)m / 6, r = (int)m - 6 * g;
    const int n = n0 + g;
    float4 xs;
    if (r == 0) xs = *(const float4*)(h0 + (size_t)n * 128 + ch * 4);
    else        xs = *(const float4*)(h1 + ((size_t)n * 5 + (r - 1)) * 128 + ch * 4);
    const int k0 = (int)ch * 4;
    AT[(k0 + 0) * 48 + m] = xs.x;
    AT[(k0 + 1) * 48 + m] = xs.y;
    AT[(k0 + 2) * 48 + m] = xs.z;
    AT[(k0 + 3) * 48 + m] = xs.w;
  }
  __syncthreads();

  // ---------------- GEMM k = 0..127 ----------------
  const float* wp = W1T + tj * 4;
  #pragma unroll 4
  for (int k = 0; k < 128; ++k) {
    const float4 w = *(const float4*)(wp + (k << 8));
    const float* ap = AT + k * 48 + m0;
    const float4 a0 = *(const float4*)(ap);
    const float4 a1 = *(const float4*)(ap + 4);
    const float4 a2 = *(const float4*)(ap + 8);
    const float av[12] = {a0.x, a0.y, a0.z, a0.w, a1.x, a1.y, a1.z, a1.w,
                          a2.x, a2.y, a2.z, a2.w};
    #pragma unroll
    for (int mm = 0; mm < 12; ++mm) {
      acc[mm][0] = fmaf(av[mm], w.x, acc[mm][0]);
      acc[mm][1] = fmaf(av[mm], w.y, acc[mm][1]);
      acc[mm][2] = fmaf(av[mm], w.z, acc[mm][2]);
      acc[mm][3] = fmaf(av[mm], w.w, acc[mm][3]);
    }
  }
  __syncthreads();

  // ---------------- stage half 1: neigh means (k = 128..255) ----------------
  for (int it = tid; it < ROWS * 32; it += BLOCK) {
    const unsigned m = (unsigned)it % 48u;
    const unsigned ch = (unsigned)it / 48u;
    const int g = (int)m / 6, r = (int)m - 6 * g;
    const int n = n0 + g;
    float4 ng;
    if (r == 0) {
      const float* b = h1 + (size_t)(n * 5) * 128 + ch * 4;
      const float4 s0 = *(const float4*)(b);
      const float4 s1 = *(const float4*)(b + 128);
      const float4 s2 = *(const float4*)(b + 256);
      const float4 s3 = *(const float4*)(b + 384);
      const float4 s4 = *(const float4*)(b + 512);
      ng.x = (s0.x + s1.x + s2.x + s3.x + s4.x) * 0.2f;
      ng.y = (s0.y + s1.y + s2.y + s3.y + s4.y) * 0.2f;
      ng.z = (s0.z + s1.z + s2.z + s3.z + s4.z) * 0.2f;
      ng.w = (s0.w + s1.w + s2.w + s3.w + s4.w) * 0.2f;
    } else {
      const size_t i = (size_t)n * 5 + (r - 1);
      const float4 a  = *(const float4*)(h2 + (2 * i) * 128 + ch * 4);
      const float4 b2 = *(const float4*)(h2 + (2 * i + 1) * 128 + ch * 4);
      ng.x = (a.x + b2.x) * 0.5f;
      ng.y = (a.y + b2.y) * 0.5f;
      ng.z = (a.z + b2.z) * 0.5f;
      ng.w = (a.w + b2.w) * 0.5f;
    }
    const int k0 = (int)ch * 4;
    AT[(k0 + 0) * 48 + m] = ng.x;
    AT[(k0 + 1) * 48 + m] = ng.y;
    AT[(k0 + 2) * 48 + m] = ng.z;
    AT[(k0 + 3) * 48 + m] = ng.w;
  }
  __syncthreads();

  // ---------------- GEMM k = 128..255 (same acc chain -> bit-identical order) ----------------
  #pragma unroll 4
  for (int k = 0; k < 128; ++k) {
    const float4 w = *(const float4*)(wp + ((k + 128) << 8));
    const float* ap = AT + k * 48 + m0;
    const float4 a0 = *(const float4*)(ap);
    const float4 a1 = *(const float4*)(ap + 4);
    const float4 a2 = *(const float4*)(ap + 8);
    const float av[12] = {a0.x, a0.y, a0.z, a0.w, a1.x, a1.y, a1.z, a1.w,
                          a2.x, a2.y, a2.z, a2.w};
    #pragma unroll
    for (int mm = 0; mm < 12; ++mm) {
      acc[mm][0] = fmaf(av[mm], w.x, acc[mm][0]);
      acc[mm][1] = fmaf(av[mm], w.y, acc[mm][1]);
      acc[mm][2] = fmaf(av[mm], w.z, acc[mm][2]);
      acc[mm][3] = fmaf(av[mm], w.w, acc[mm][3]);
    }
  }
  __syncthreads();   // AT dead; A2 alias becomes writable

  // ---------------- out_s via x/t lane exchange; fold into h0p / neigh-sum ----------------
  // lane tj<32 holds x-cols (4tj..4tj+3); lane tj+32 holds matching t-cols (+128)
  float h0p[2][4], nb[2][4];
  #pragma unroll
  for (int mm = 0; mm < 12; ++mm) {
    const int gg = mm / 6;        // static
    const int r = mm - 6 * gg;    // static
    #pragma unroll
    for (int q = 0; q < 4; ++q) {
      const float o = __shfl_xor(acc[mm][q], 32, 64);
      const float sv = sigm(acc[mm][q]) * (o >= 1.0f ? 1.0f : 0.0f);
      if (r == 0) { h0p[gg][q] = sv; }
      else if (r == 1) { nb[gg][q] = sv; }
      else { nb[gg][q] += sv; }
    }
  }

  if (tj < 32) {
    #pragma unroll
    for (int gg = 0; gg < 2; ++gg) {
      const int g = 2 * tm + gg;
      float4 v;
      v.x = h0p[gg][0]; v.y = h0p[gg][1]; v.z = h0p[gg][2]; v.w = h0p[gg][3];
      *(float4*)(A2 + g * 260 + 4 * tj) = v;
      float4 nv;
      nv.x = nb[gg][0] * 0.2f; nv.y = nb[gg][1] * 0.2f;
      nv.z = nb[gg][2] * 0.2f; nv.w = nb[gg][3] * 0.2f;
      *(float4*)(A2 + g * 260 + 128 + 4 * tj) = nv;
    }
  }
  __syncthreads();

  // ---------------- layer-2: M=8, N=128 (64 sig | 64 spk), K=256 ----------------
  // wave tm -> rows 2*tm, 2*tm+1; lane: half = lane>>5 (0:x-cols, 1:t-cols), c2 = lane&31
  const int lane = tid & 63;
  const int half = lane >> 5;
  const int c2 = lane & 31;
  const int col = half * 64 + 2 * c2;   // cols col, col+1
  const int g0 = 2 * tm;
  float b00 = 0.f, b01 = 0.f, b10 = 0.f, b11 = 0.f;
  const float* w2 = W2T + col;
  const float* a0p = A2 + g0 * 260;
  const float* a1p = A2 + (g0 + 1) * 260;
  #pragma unroll 4
  for (int k4 = 0; k4 < 256; k4 += 4) {
    const float4 a0v = *(const float4*)(a0p + k4);
    const float4 a1v = *(const float4*)(a1p + k4);
    const float a0s[4] = {a0v.x, a0v.y, a0v.z, a0v.w};
    const float a1s[4] = {a1v.x, a1v.y, a1v.z, a1v.w};
    #pragma unroll
    for (int kk = 0; kk < 4; ++kk) {
      const float2 ww = *(const float2*)(w2 + ((k4 + kk) << 7));
      b00 = fmaf(a0s[kk], ww.x, b00);
      b01 = fmaf(a0s[kk], ww.y, b01);
      b10 = fmaf(a1s[kk], ww.x, b10);
      b11 = fmaf(a1s[kk], ww.y, b11);
    }
  }
  // x/t exchange within wave (lane ^ 32)
  const float t00 = __shfl_xor(b00, 32, 64);
  const float t01 = __shfl_xor(b01, 32, 64);
  const float t10 = __shfl_xor(b10, 32, 64);
  const float t11 = __shfl_xor(b11, 32, 64);
  if (half == 0) {
    float2 o0, o1;
    o0.x = sigm(b00) * (t00 >= 1.0f ? 1.0f : 0.0f);
    o0.y = sigm(b01) * (t01 >= 1.0f ? 1.0f : 0.0f);
    o1.x = sigm(b10) * (t10 >= 1.0f ? 1.0f : 0.0f);
    o1.y = sigm(b11) * (t11 >= 1.0f ? 1.0f : 0.0f);
    *(float2*)(out + (size_t)(n0 + g0) * 64 + 2 * c2) = o0;
    *(float2*)(out + (size_t)(n0 + g0 + 1) * 64 + 2 * c2) = o1;
  }
}

extern "C" void kernel_launch(void* const* d_in, const int* in_sizes, int n_in,
                              void* d_out, int out_size, void* d_ws, size_t ws_size,
                              hipStream_t stream) {
  const float* h0 = (const float*)d_in[0];
  const float* h1 = (const float*)d_in[1];
  const float* h2 = (const float*)d_in[2];
  float* W1T = (float*)d_ws;             // 256*256 floats
  float* W2T = W1T + 256 * 256;          // 256*128 floats

  const int pack_items = 256 * 256 + 256 * 128;
  pack_weights_k<<<(pack_items + BLOCK - 1) / BLOCK, BLOCK, 0, stream>>>(
      (const float*)d_in[3], (const float*)d_in[4], (const float*)d_in[5],
      (const float*)d_in[6], (const float*)d_in[7], (const float*)d_in[8],
      (const float*)d_in[9], (const float*)d_in[10], W1T, W2T);

  signn_fused_k<<<100000 / GG, BLOCK, 0, stream>>>(h0, h1, h2, W1T, W2T,
                                                   (float*)d_out);
}